// Round 5
// baseline (417.841 us; speedup 1.0000x reference)
//
#include <hip/hip_runtime.h>

// VQ: N=262144 vectors (64x4096), D=64, K=512 codewords, fp32.
// out (float32): quantized[16777216] | indices[262144] (as float) | loss[1]
//
// R5: R4 minus the x LDS tile. DS-pipe cost is per-INSTRUCTION (~12 cyc per
// wave b128), so R4's 16 ds_read/t4 capped VALU at 512/768 = 67% (measured
// 67.4%). Now af (x fragments) come straight from global via L1/VMEM — a
// separate pipe; 16 lanes share each address -> 64 B/wave-instr, L1-trivial.
// Remaining DS = bf only (8 b128/t4) -> FMA:DS = 32:1 > 24:1 -> VALU-bound.
// Same fma chain order as R4 -> bitwise-identical scores.

#define NVEC    262144
#define DDIM    64
#define KCW     512
#define BM      128
#define BN      128
#define NCHUNK  (KCW / BN)
#define BSTRIDE 68
#define LOSS_SCALE (0.25f / 16777216.0f)   // COMMITMENT_COST / (N*D)

__global__ void csq_zero_kernel(const float* __restrict__ cw,
                                float* __restrict__ csq,
                                float* __restrict__ loss_slot) {
    int n = blockIdx.x * blockDim.x + threadIdx.x;
    if (n < KCW) {
        const float4* r = (const float4*)(cw + n * DDIM);
        float s = 0.f;
        #pragma unroll
        for (int t = 0; t < 16; ++t) {
            float4 v = r[t];
            s += v.x * v.x + v.y * v.y + v.z * v.z + v.w * v.w;
        }
        csq[n] = s;
    }
    if (n == 0) *loss_slot = 0.f;   // d_out poisoned before every launch
}

__global__ __launch_bounds__(256, 1)
void vq_kernel(const float* __restrict__ x, const float* __restrict__ cw,
               const float* __restrict__ csq,
               float* __restrict__ out_q, float* __restrict__ out_idx,
               float* __restrict__ out_loss) {
    __shared__ float Bs[BN * BSTRIDE];     // 34 KB, Bs[n*68+k], 2-way only (free)
    __shared__ float csqs[KCW];            // 2 KB
    __shared__ int   win[BM];
    __shared__ float red[4];

    const int tid = threadIdx.x;
    const int tx  = tid & 15;              // codeword group (TN=8: n = tx+16j)
    const int ty  = tid >> 4;              // row group (TM=8: m = ty*8+i)
    const long base_row = (long)blockIdx.x * BM;

    // this thread's 8 x-rows; all af loads = one base + imm offsets (<4KB)
    const float* __restrict__ xrow = x + (base_row + ty * 8) * DDIM;

    csqs[tid]       = csq[tid];
    csqs[tid + 256] = csq[tid + 256];

    float best[8]; int bidx[8];
    #pragma unroll
    for (int i = 0; i < 8; ++i) { best[i] = 3.402823466e38f; bidx[i] = 0; }

    for (int ch = 0; ch < NCHUNK; ++ch) {
        __syncthreads();   // prior chunk consumed (first iter: covers csqs)
        // ---- stage B chunk: 128 codewords x 64, coalesced, stride 68 ----
        {
            int n = tid >> 1, h = tid & 1;
            const float4* g = (const float4*)(cw + (ch * BN + n) * DDIM + h * 32);
            float* bp = &Bs[n * BSTRIDE + h * 32];
            #pragma unroll
            for (int t = 0; t < 8; ++t) *(float4*)(bp + 4 * t) = g[t];
        }
        __syncthreads();

        float acc[8][8];
        #pragma unroll
        for (int i = 0; i < 8; ++i)
            #pragma unroll
            for (int j = 0; j < 8; ++j) acc[i][j] = 0.f;

        #pragma unroll 4
        for (int t4 = 0; t4 < 16; ++t4) {
            float4 af[8];                  // af[r] = x[row ty*8+r][t4*4..+3] (global/L1)
            #pragma unroll
            for (int r = 0; r < 8; ++r)
                af[r] = *(const float4*)(xrow + r * DDIM + t4 * 4);
            float4 bf[8];                  // bf[j] = depths t4*4.. of codeword tx+16j
            #pragma unroll
            for (int j = 0; j < 8; ++j)
                bf[j] = *(const float4*)&Bs[(tx + 16 * j) * BSTRIDE + t4 * 4];

            const float* afp = (const float*)af;
            #pragma unroll
            for (int j = 0; j < 8; ++j) {
                const float* bp = (const float*)&bf[j];
                #pragma unroll
                for (int k = 0; k < 4; ++k) {
                    float b = bp[k];
                    #pragma unroll
                    for (int r = 0; r < 8; ++r)
                        acc[r][j] = __builtin_fmaf(afp[r * 4 + k], b, acc[r][j]);
                }
            }
        }

        // ---- score + running argmin (j ascending => n ascending per lane) ----
        #pragma unroll
        for (int j = 0; j < 8; ++j) {
            int gn = ch * BN + tx + 16 * j;
            float cs = csqs[gn];
            #pragma unroll
            for (int i = 0; i < 8; ++i) {
                float sc = __builtin_fmaf(-2.f, acc[i][j], cs);
                if (sc < best[i]) { best[i] = sc; bidx[i] = gn; }
            }
        }
    }

    // ---- cross-lane argmin over the 16 tx lanes, per row ----
    #pragma unroll
    for (int i = 0; i < 8; ++i) {
        float d = best[i]; int ix = bidx[i];
        #pragma unroll
        for (int off = 8; off > 0; off >>= 1) {
            float d2 = __shfl_down(d, off, 16);
            int   i2 = __shfl_down(ix, off, 16);
            if (d2 < d || (d2 == d && i2 < ix)) { d = d2; ix = i2; }
        }
        if (tx == 0) {
            int m = ty * 8 + i;
            win[m] = ix;
            out_idx[base_row + m] = (float)ix;
        }
    }
    __syncthreads();

    // ---- quantized write + elementwise commitment loss (x re-read, L1/L2-hot) ----
    float ls = 0.f;
    {
        int m = tid >> 1, h = tid & 1;
        int w = win[m];
        const float4* qg = (const float4*)(cw + w * DDIM + h * 32);  // L2-hot
        const float4* xg = (const float4*)(x + (base_row + m) * DDIM + h * 32);
        float4* og = (float4*)(out_q + (base_row + m) * DDIM + h * 32);
        #pragma unroll
        for (int t = 0; t < 8; ++t) {
            float4 q = qg[t];
            float4 xv = xg[t];
            og[t] = q;
            float d0 = q.x - xv.x, d1 = q.y - xv.y;
            float d2 = q.z - xv.z, d3 = q.w - xv.w;
            ls += d0 * d0 + d1 * d1 + d2 * d2 + d3 * d3;
        }
    }
    #pragma unroll
    for (int off = 32; off > 0; off >>= 1) ls += __shfl_down(ls, off, 64);
    if ((tid & 63) == 0) red[tid >> 6] = ls;
    __syncthreads();
    if (tid == 0)
        atomicAdd(out_loss, ((red[0] + red[1]) + (red[2] + red[3])) * LOSS_SCALE);
}

extern "C" void kernel_launch(void* const* d_in, const int* in_sizes, int n_in,
                              void* d_out, int out_size, void* d_ws, size_t ws_size,
                              hipStream_t stream) {
    const float* x  = (const float*)d_in[0];   // (64,4096,64) fp32
    const float* cw = (const float*)d_in[1];   // (512,64) fp32
    float* out      = (float*)d_out;
    float* out_q    = out;                      // 16777216
    float* out_idx  = out + 16777216;           // 262144
    float* out_loss = out + 16777216 + 262144;  // 1
    float* csq      = (float*)d_ws;             // 512 floats scratch

    csq_zero_kernel<<<8, 64, 0, stream>>>(cw, csq, out_loss);
    vq_kernel<<<NVEC / BM, 256, 0, stream>>>(x, cw, csq, out_q, out_idx, out_loss);
}

// Round 7
// 385.048 us; speedup vs baseline: 1.0852x; 1.0852x over previous
//
#include <hip/hip_runtime.h>

// VQ: N=262144 vectors (64x4096), D=64, K=512 codewords, fp32.
// out (float32): quantized[16777216] | indices[262144] (as float) | loss[1]
//
// R7: R4's verified tile (TM=TN=8, BM=BN=128) with af moved OFF the DS pipe.
//  - bf (codewords) from LDS: 8 ds_read_b128/t4 -> DS demand 75% of window,
//    no longer the binding pipe (R4's 16/t4 capped VALU at 67%, measured).
//  - af (x fragments) from global via L1/L2 with a ping-pong register buffer
//    prefetched one t4-step (~512 cyc) ahead — fixes R5's exposed latency.
//    af addresses are periodic in t4 (x fixed across chunks), so t4=14's
//    phase-B prefetch of depth 0 feeds the next chunk too.
//  - FMA chain order identical to R4 -> bitwise-identical argmin.
//  - Scalar-pipe (s_load) path abandoned: SMEM returns are OUT-OF-ORDER,
//    lgkmcnt(N!=0) is unsound for s_load (R6 failure).

#define NVEC    262144
#define DDIM    64
#define KCW     512
#define BM      128
#define BN      128
#define NCHUNK  (KCW / BN)
#define BSTRIDE 68
#define LOSS_SCALE (0.25f / 16777216.0f)   // COMMITMENT_COST / (N*D)

__global__ void csq_zero_kernel(const float* __restrict__ cw,
                                float* __restrict__ csq,
                                float* __restrict__ loss_slot) {
    int n = blockIdx.x * blockDim.x + threadIdx.x;
    if (n < KCW) {
        const float4* r = (const float4*)(cw + n * DDIM);
        float s = 0.f;
        #pragma unroll
        for (int t = 0; t < 16; ++t) {
            float4 v = r[t];
            s += v.x * v.x + v.y * v.y + v.z * v.z + v.w * v.w;
        }
        csq[n] = s;
    }
    if (n == 0) *loss_slot = 0.f;   // d_out poisoned before every launch
}

// 256 FMAs of one t4-step: af buffer AF (8 float4: row r, 4 depths) x bf[8].
// Loop order (j,k,i) matches R4 exactly -> bitwise-identical accumulation.
#define T4_FMA(AF)                                                   \
    _Pragma("unroll")                                                \
    for (int j = 0; j < 8; ++j) {                                    \
        const float* bp = (const float*)&bf[j];                      \
        _Pragma("unroll")                                            \
        for (int k = 0; k < 4; ++k) {                                \
            float b = bp[k];                                         \
            _Pragma("unroll")                                        \
            for (int i = 0; i < 8; ++i)                              \
                acc[i][j] = __builtin_fmaf(                          \
                    ((const float*)&AF[i])[k], b, acc[i][j]);        \
        }                                                            \
    }

__global__ __launch_bounds__(256, 1)
void vq_kernel(const float* __restrict__ x, const float* __restrict__ cw,
               const float* __restrict__ csq,
               float* __restrict__ out_q, float* __restrict__ out_idx,
               float* __restrict__ out_loss) {
    __shared__ float Bs[BN * BSTRIDE];     // 34 KB, Bs[n*68+k], 2-way only (free)
    __shared__ float csqs[KCW];            // 2 KB
    __shared__ int   win[BM];
    __shared__ float red[4];

    const int tid = threadIdx.x;
    const int tx  = tid & 15;              // codeword group (TN=8: n = tx+16j)
    const int ty  = tid >> 4;              // row group (TM=8: m = ty*8+i)
    const long base_row = (long)blockIdx.x * BM;

    // this thread's 8 x-rows; af loads = base + small immediate offsets
    const float* __restrict__ xrow = x + (base_row + ty * 8) * DDIM;

    csqs[tid]       = csq[tid];
    csqs[tid + 256] = csq[tid + 256];

    // ---- preload af ping buffer with depth group 0 ----
    float4 afa[8], afb[8];
    #pragma unroll
    for (int r = 0; r < 8; ++r)
        afa[r] = *(const float4*)(xrow + r * DDIM);

    float best[8]; int bidx[8];
    #pragma unroll
    for (int i = 0; i < 8; ++i) { best[i] = 3.402823466e38f; bidx[i] = 0; }

    for (int ch = 0; ch < NCHUNK; ++ch) {
        __syncthreads();   // prior chunk consumed (first iter: covers csqs)
        // ---- stage B chunk: 128 codewords x 64, coalesced, stride 68 ----
        {
            int n = tid >> 1, h = tid & 1;
            const float4* g = (const float4*)(cw + (ch * BN + n) * DDIM + h * 32);
            float* bp = &Bs[n * BSTRIDE + h * 32];
            #pragma unroll
            for (int t = 0; t < 8; ++t) *(float4*)(bp + 4 * t) = g[t];
        }
        __syncthreads();

        float acc[8][8];
        #pragma unroll
        for (int i = 0; i < 8; ++i)
            #pragma unroll
            for (int j = 0; j < 8; ++j) acc[i][j] = 0.f;

        for (int t4 = 0; t4 < 16; t4 += 2) {
            float4 bf[8];
            // ---- phase A: prefetch depths (t4+1), compute on afa (t4) ----
            {
                const float* xp = xrow + (t4 + 1) * 4;
                #pragma unroll
                for (int r = 0; r < 8; ++r)
                    afb[r] = *(const float4*)(xp + r * DDIM);
            }
            #pragma unroll
            for (int j = 0; j < 8; ++j)
                bf[j] = *(const float4*)&Bs[(tx + 16 * j) * BSTRIDE + t4 * 4];
            T4_FMA(afa)

            // ---- phase B: prefetch depths ((t4+2)&15), compute on afb ----
            {
                const float* xp = xrow + ((t4 + 2) & 15) * 4;
                #pragma unroll
                for (int r = 0; r < 8; ++r)
                    afa[r] = *(const float4*)(xp + r * DDIM);
            }
            #pragma unroll
            for (int j = 0; j < 8; ++j)
                bf[j] = *(const float4*)&Bs[(tx + 16 * j) * BSTRIDE + (t4 + 1) * 4];
            T4_FMA(afb)
        }

        // ---- score + running argmin (j ascending => n ascending per lane) ----
        #pragma unroll
        for (int j = 0; j < 8; ++j) {
            int gn = ch * BN + tx + 16 * j;
            float cs = csqs[gn];
            #pragma unroll
            for (int i = 0; i < 8; ++i) {
                float sc = __builtin_fmaf(-2.f, acc[i][j], cs);
                if (sc < best[i]) { best[i] = sc; bidx[i] = gn; }
            }
        }
    }

    // ---- cross-lane argmin over the 16 tx lanes, per row ----
    #pragma unroll
    for (int i = 0; i < 8; ++i) {
        float d = best[i]; int ix = bidx[i];
        #pragma unroll
        for (int off = 8; off > 0; off >>= 1) {
            float d2 = __shfl_down(d, off, 16);
            int   i2 = __shfl_down(ix, off, 16);
            if (d2 < d || (d2 == d && i2 < ix)) { d = d2; ix = i2; }
        }
        if (tx == 0) {
            int m = ty * 8 + i;
            win[m] = ix;
            out_idx[base_row + m] = (float)ix;
        }
    }
    __syncthreads();

    // ---- quantized write + elementwise commitment loss (x re-read, cache-hot) ----
    float ls = 0.f;
    {
        int m = tid >> 1, h = tid & 1;
        int w = win[m];
        const float4* qg = (const float4*)(cw + w * DDIM + h * 32);  // L2-hot
        const float4* xg = (const float4*)(x + (base_row + m) * DDIM + h * 32);
        float4* og = (float4*)(out_q + (base_row + m) * DDIM + h * 32);
        #pragma unroll
        for (int t = 0; t < 8; ++t) {
            float4 q = qg[t];
            float4 xv = xg[t];
            og[t] = q;
            float d0 = q.x - xv.x, d1 = q.y - xv.y;
            float d2 = q.z - xv.z, d3 = q.w - xv.w;
            ls += d0 * d0 + d1 * d1 + d2 * d2 + d3 * d3;
        }
    }
    #pragma unroll
    for (int off = 32; off > 0; off >>= 1) ls += __shfl_down(ls, off, 64);
    if ((tid & 63) == 0) red[tid >> 6] = ls;
    __syncthreads();
    if (tid == 0)
        atomicAdd(out_loss, ((red[0] + red[1]) + (red[2] + red[3])) * LOSS_SCALE);
}

extern "C" void kernel_launch(void* const* d_in, const int* in_sizes, int n_in,
                              void* d_out, int out_size, void* d_ws, size_t ws_size,
                              hipStream_t stream) {
    const float* x  = (const float*)d_in[0];   // (64,4096,64) fp32
    const float* cw = (const float*)d_in[1];   // (512,64) fp32
    float* out      = (float*)d_out;
    float* out_q    = out;                      // 16777216
    float* out_idx  = out + 16777216;           // 262144
    float* out_loss = out + 16777216 + 262144;  // 1
    float* csq      = (float*)d_ws;             // 512 floats scratch

    csq_zero_kernel<<<8, 64, 0, stream>>>(cw, csq, out_loss);
    vq_kernel<<<NVEC / BM, 256, 0, stream>>>(x, cw, csq, out_q, out_idx, out_loss);
}